// Round 2
// baseline (486.910 us; speedup 1.0000x reference)
//
#include <hip/hip_runtime.h>
#include <hip/hip_bf16.h>
#include <math.h>

// Fully-fused MLP (instant-NGP style) for VectorField.
// out = silu(silu(silu([x|enc]@W0+b0)@W1+b1)@W2+b2)@W3 + b3
// One persistent block per 128 rows: activations in swizzled LDS (128KB),
// weights pre-shuffled to MFMA-fragment order -> global->reg coalesced loads
// (no LDS staging, no K-loop barriers in layers 1-3).

#define T_SIZE 524288   // 2^19
#define T_MASK (T_SIZE - 1)

typedef _Float16 f16;
typedef _Float16 f16x8 __attribute__((ext_vector_type(8)));
typedef _Float16 f16x4 __attribute__((ext_vector_type(4)));
typedef float f32x4 __attribute__((ext_vector_type(4)));

struct Scales { float s[16]; };

// ---------------- hash encode -> Enc[B][64] f16 ----------------
__global__ void hash_enc(const float* __restrict__ t, const float* __restrict__ cond,
                         const float* __restrict__ tables, f16* __restrict__ Enc,
                         Scales sc) {
  int tid = blockIdx.x * blockDim.x + threadIdx.x;   // B*16 threads
  int b = tid >> 4, l = tid & 15;
  float c0 = cond[2 * b], c1 = cond[2 * b + 1], c2 = t[b];
  float s = sc.s[l];
  float xf0 = c0 * s, xf1 = c1 * s, xf2 = c2 * s;
  float xl0 = floorf(xf0), xl1 = floorf(xf1), xl2 = floorf(xf2);
  float w0 = xf0 - xl0, w1 = xf1 - xl1, w2 = xf2 - xl2;
  unsigned xi0 = (unsigned)xl0, xi1 = (unsigned)xl1, xi2 = (unsigned)xl2;

  const float4* tl = (const float4*)tables + (size_t)l * T_SIZE;
  float a0 = 0.f, a1 = 0.f, a2 = 0.f, a3 = 0.f;
#pragma unroll
  for (int c = 0; c < 8; ++c) {
    unsigned ax = (c >> 2) & 1u, ay = (c >> 1) & 1u, az = c & 1u;
    unsigned hh = (xi0 + ax) ^ ((xi1 + ay) * 2654435761u) ^ ((xi2 + az) * 805459861u);
    float4 f = tl[hh & T_MASK];
    float wcw = (ax ? w0 : 1.f - w0) * (ay ? w1 : 1.f - w1) * (az ? w2 : 1.f - w2);
    a0 += wcw * f.x; a1 += wcw * f.y; a2 += wcw * f.z; a3 += wcw * f.w;
  }
  f16x4 o = { (f16)a0, (f16)a1, (f16)a2, (f16)a3 };
  *(f16x4*)(Enc + (size_t)b * 64 + l * 4) = o;
}

// ---------------- weight -> fragment-linear f16 ----------------
// Wf[frag][lane][8] where frag = nblk*(K/32)+ks; element (lane,j) =
// W[ks*32 + (lane>>4)*8 + j][nblk*16 + (lane&15)]  (W is [K][N] fp32)
__global__ void wfrag(const float* __restrict__ W, f16* __restrict__ Wf, int K, int N) {
  int tid = blockIdx.x * 256 + threadIdx.x;
  int lane = tid & 63, frag = tid >> 6;
  int KS = K >> 5;
  int nblk = frag / KS, ks = frag - nblk * KS;
  if (nblk * 16 >= N) return;
  int n = nblk * 16 + (lane & 15);
  int kb = ks * 32 + (lane >> 4) * 8;
  f16x8 v;
#pragma unroll
  for (int j = 0; j < 8; ++j) v[j] = (f16)W[(size_t)(kb + j) * N + n];
  *(f16x8*)(Wf + (size_t)frag * 512 + lane * 8) = v;
}

// ---------------- fused MLP ----------------
__global__ __launch_bounds__(512, 2) void fused_mlp(
    const float* __restrict__ x, const f16* __restrict__ Enc,
    const f16* __restrict__ Wf0, const f16* __restrict__ Wf1,
    const f16* __restrict__ Wf2, const f16* __restrict__ Wf3,
    const float* __restrict__ b0, const float* __restrict__ b1,
    const float* __restrict__ b2, const float* __restrict__ b3,
    float* __restrict__ out) {
  __shared__ f16 act[128 * 512];          // 128 KB, swizzled: idx = r*512 + (c ^ ((r&7)<<3))
  f16* stg = act;                         // layer-0 staging alias: [128][32], c ^= (r>>1)&3

  const int tid = threadIdx.x;
  const int wave = tid >> 6, lane = tid & 63;
  const int l16 = lane & 15, lhi = lane >> 4;
  const int rowBase = blockIdx.x * 128;

  // layer-0 staging coords: thread t -> row sr, logical chunk sc (8 f16)
  const int sr = tid >> 2, sc = tid & 3;
  f16* stgW = stg + sr * 32 + 8 * (sc ^ ((sr >> 1) & 3));

  f32x4 acc[8][4];
  f16x8 bfA[4], bfB[4];

  // ================= Layer 0: K = 832 (768 x + 64 enc) =================
#pragma unroll
  for (int mi = 0; mi < 8; ++mi)
#pragma unroll
    for (int ni = 0; ni < 4; ++ni) acc[mi][ni] = (f32x4){0.f, 0.f, 0.f, 0.f};

  {  // stage ks=0
    const float* xp = x + (size_t)(rowBase + sr) * 768 + sc * 8;
    float4 a = *(const float4*)xp, b = *(const float4*)(xp + 4);
    f16x8 v = { (f16)a.x, (f16)a.y, (f16)a.z, (f16)a.w,
                (f16)b.x, (f16)b.y, (f16)b.z, (f16)b.w };
    *(f16x8*)stgW = v;
  }
#pragma unroll
  for (int ni = 0; ni < 4; ++ni)
    bfA[ni] = *(const f16x8*)(Wf0 + ((size_t)(wave * 4 + ni) * 26) * 512 + lane * 8);
  __syncthreads();

  float xr[8];
  f16x8 er;
  for (int ks = 0; ks < 26; ++ks) {
    const int nxt = ks + 1;
    const bool hasNext = nxt < 26;
    if (hasNext) {
      if (nxt < 24) {
        const float* xp = x + (size_t)(rowBase + sr) * 768 + nxt * 32 + sc * 8;
        float4 a = *(const float4*)xp, b = *(const float4*)(xp + 4);
        xr[0] = a.x; xr[1] = a.y; xr[2] = a.z; xr[3] = a.w;
        xr[4] = b.x; xr[5] = b.y; xr[6] = b.z; xr[7] = b.w;
      } else {
        er = *(const f16x8*)(Enc + (size_t)(rowBase + sr) * 64 + (nxt - 24) * 32 + sc * 8);
      }
#pragma unroll
      for (int ni = 0; ni < 4; ++ni)
        bfB[ni] = *(const f16x8*)(Wf0 + ((size_t)(wave * 4 + ni) * 26 + nxt) * 512 + lane * 8);
    }
    f16x8 af[8];
#pragma unroll
    for (int mi = 0; mi < 8; ++mi) {
      int r = mi * 16 + l16;
      af[mi] = *(const f16x8*)(stg + r * 32 + 8 * (lhi ^ ((r >> 1) & 3)));
    }
#pragma unroll
    for (int mi = 0; mi < 8; ++mi)
#pragma unroll
      for (int ni = 0; ni < 4; ++ni)
        acc[mi][ni] = __builtin_amdgcn_mfma_f32_16x16x32_f16(af[mi], bfA[ni], acc[mi][ni], 0, 0, 0);
    __syncthreads();                      // all reads of stg complete
    if (hasNext) {
      f16x8 v;
      if (nxt < 24) {
        f16x8 c = { (f16)xr[0], (f16)xr[1], (f16)xr[2], (f16)xr[3],
                    (f16)xr[4], (f16)xr[5], (f16)xr[6], (f16)xr[7] };
        v = c;
      } else {
        v = er;
      }
      *(f16x8*)stgW = v;
#pragma unroll
      for (int ni = 0; ni < 4; ++ni) bfA[ni] = bfB[ni];
    }
    __syncthreads();                      // stage visible
  }

  {  // epilogue L0 -> act (silu)
    float bv[4];
#pragma unroll
    for (int ni = 0; ni < 4; ++ni) bv[ni] = b0[wave * 64 + ni * 16 + l16];
#pragma unroll
    for (int mi = 0; mi < 8; ++mi)
#pragma unroll
      for (int ni = 0; ni < 4; ++ni)
#pragma unroll
        for (int r = 0; r < 4; ++r) {
          int row = mi * 16 + lhi * 4 + r;
          int col = wave * 64 + ni * 16 + l16;
          float v = acc[mi][ni][r] + bv[ni];
          v = v / (1.f + __expf(-v));
          act[row * 512 + (col ^ ((row & 7) << 3))] = (f16)v;
        }
    __syncthreads();
  }

  // ================= Layers 1,2: K=512, act-resident =================
  auto mlp_layer = [&](const f16* __restrict__ Wf, const float* __restrict__ bias) {
#pragma unroll
    for (int mi = 0; mi < 8; ++mi)
#pragma unroll
      for (int ni = 0; ni < 4; ++ni) acc[mi][ni] = (f32x4){0.f, 0.f, 0.f, 0.f};
#pragma unroll
    for (int ni = 0; ni < 4; ++ni)
      bfA[ni] = *(const f16x8*)(Wf + ((size_t)(wave * 4 + ni) * 16) * 512 + lane * 8);
    for (int ks = 0; ks < 16; ++ks) {
      if (ks + 1 < 16) {
#pragma unroll
        for (int ni = 0; ni < 4; ++ni)
          bfB[ni] = *(const f16x8*)(Wf + ((size_t)(wave * 4 + ni) * 16 + ks + 1) * 512 + lane * 8);
      }
      f16x8 af[8];
#pragma unroll
      for (int mi = 0; mi < 8; ++mi) {
        int r = mi * 16 + l16;
        af[mi] = *(const f16x8*)(act + r * 512 + ((ks * 32 + lhi * 8) ^ ((r & 7) << 3)));
      }
#pragma unroll
      for (int mi = 0; mi < 8; ++mi)
#pragma unroll
        for (int ni = 0; ni < 4; ++ni)
          acc[mi][ni] = __builtin_amdgcn_mfma_f32_16x16x32_f16(af[mi], bfA[ni], acc[mi][ni], 0, 0, 0);
      if (ks + 1 < 16) {
#pragma unroll
        for (int ni = 0; ni < 4; ++ni) bfA[ni] = bfB[ni];
      }
    }
    float bv[4];
#pragma unroll
    for (int ni = 0; ni < 4; ++ni) bv[ni] = bias[wave * 64 + ni * 16 + l16];
    __syncthreads();                      // all act reads complete before overwrite
#pragma unroll
    for (int mi = 0; mi < 8; ++mi)
#pragma unroll
      for (int ni = 0; ni < 4; ++ni)
#pragma unroll
        for (int r = 0; r < 4; ++r) {
          int row = mi * 16 + lhi * 4 + r;
          int col = wave * 64 + ni * 16 + l16;
          float v = acc[mi][ni][r] + bv[ni];
          v = v / (1.f + __expf(-v));
          act[row * 512 + (col ^ ((row & 7) << 3))] = (f16)v;
        }
    __syncthreads();
  };
  mlp_layer(Wf1, b1);
  mlp_layer(Wf2, b2);

  // ================= Layer 3: K=512, N=768, write out =================
  // pass A: cols 0..511 (4 frags/wave)
#pragma unroll
  for (int mi = 0; mi < 8; ++mi)
#pragma unroll
    for (int ni = 0; ni < 4; ++ni) acc[mi][ni] = (f32x4){0.f, 0.f, 0.f, 0.f};
#pragma unroll
  for (int ni = 0; ni < 4; ++ni)
    bfA[ni] = *(const f16x8*)(Wf3 + ((size_t)(wave * 4 + ni) * 16) * 512 + lane * 8);
  for (int ks = 0; ks < 16; ++ks) {
    if (ks + 1 < 16) {
#pragma unroll
      for (int ni = 0; ni < 4; ++ni)
        bfB[ni] = *(const f16x8*)(Wf3 + ((size_t)(wave * 4 + ni) * 16 + ks + 1) * 512 + lane * 8);
    }
    f16x8 af[8];
#pragma unroll
    for (int mi = 0; mi < 8; ++mi) {
      int r = mi * 16 + l16;
      af[mi] = *(const f16x8*)(act + r * 512 + ((ks * 32 + lhi * 8) ^ ((r & 7) << 3)));
    }
#pragma unroll
    for (int mi = 0; mi < 8; ++mi)
#pragma unroll
      for (int ni = 0; ni < 4; ++ni)
        acc[mi][ni] = __builtin_amdgcn_mfma_f32_16x16x32_f16(af[mi], bfA[ni], acc[mi][ni], 0, 0, 0);
    if (ks + 1 < 16) {
#pragma unroll
      for (int ni = 0; ni < 4; ++ni) bfA[ni] = bfB[ni];
    }
  }
  {
    float bv[4];
#pragma unroll
    for (int ni = 0; ni < 4; ++ni) bv[ni] = b3[wave * 64 + ni * 16 + l16];
#pragma unroll
    for (int mi = 0; mi < 8; ++mi)
#pragma unroll
      for (int ni = 0; ni < 4; ++ni)
#pragma unroll
        for (int r = 0; r < 4; ++r) {
          int row = rowBase + mi * 16 + lhi * 4 + r;
          int col = wave * 64 + ni * 16 + l16;
          out[(size_t)row * 768 + col] = acc[mi][ni][r] + bv[ni];
        }
  }

  // pass B: cols 512..767 (2 frags/wave)
#pragma unroll
  for (int mi = 0; mi < 8; ++mi)
#pragma unroll
    for (int ni = 0; ni < 2; ++ni) acc[mi][ni] = (f32x4){0.f, 0.f, 0.f, 0.f};
#pragma unroll
  for (int ni = 0; ni < 2; ++ni)
    bfA[ni] = *(const f16x8*)(Wf3 + ((size_t)(32 + wave * 2 + ni) * 16) * 512 + lane * 8);
  for (int ks = 0; ks < 16; ++ks) {
    if (ks + 1 < 16) {
#pragma unroll
      for (int ni = 0; ni < 2; ++ni)
        bfB[ni] = *(const f16x8*)(Wf3 + ((size_t)(32 + wave * 2 + ni) * 16 + ks + 1) * 512 + lane * 8);
    }
    f16x8 af[8];
#pragma unroll
    for (int mi = 0; mi < 8; ++mi) {
      int r = mi * 16 + l16;
      af[mi] = *(const f16x8*)(act + r * 512 + ((ks * 32 + lhi * 8) ^ ((r & 7) << 3)));
    }
#pragma unroll
    for (int mi = 0; mi < 8; ++mi)
#pragma unroll
      for (int ni = 0; ni < 2; ++ni)
        acc[mi][ni] = __builtin_amdgcn_mfma_f32_16x16x32_f16(af[mi], bfA[ni], acc[mi][ni], 0, 0, 0);
    if (ks + 1 < 16) {
#pragma unroll
      for (int ni = 0; ni < 2; ++ni) bfA[ni] = bfB[ni];
    }
  }
  {
    float bv[2];
#pragma unroll
    for (int ni = 0; ni < 2; ++ni) bv[ni] = b3[512 + wave * 32 + ni * 16 + l16];
#pragma unroll
    for (int mi = 0; mi < 8; ++mi)
#pragma unroll
      for (int ni = 0; ni < 2; ++ni)
#pragma unroll
        for (int r = 0; r < 4; ++r) {
          int row = rowBase + mi * 16 + lhi * 4 + r;
          int col = 512 + wave * 32 + ni * 16 + l16;
          out[(size_t)row * 768 + col] = acc[mi][ni][r] + bv[ni];
        }
  }
}

// ---------------- launch ----------------
extern "C" void kernel_launch(void* const* d_in, const int* in_sizes, int n_in,
                              void* d_out, int out_size, void* d_ws, size_t ws_size,
                              hipStream_t stream) {
  const float* t    = (const float*)d_in[0];
  const float* x    = (const float*)d_in[1];
  const float* cond = (const float*)d_in[2];
  const float* tab  = (const float*)d_in[3];
  const float* W0   = (const float*)d_in[4];
  const float* b0   = (const float*)d_in[5];
  const float* W1   = (const float*)d_in[6];
  const float* b1   = (const float*)d_in[7];
  const float* W2   = (const float*)d_in[8];
  const float* b2   = (const float*)d_in[9];
  const float* W3   = (const float*)d_in[10];
  const float* b3   = (const float*)d_in[11];
  float* out = (float*)d_out;
  (void)in_sizes; (void)n_in; (void)out_size; (void)ws_size;

  char* ws = (char*)d_ws;
  f16* Wf0 = (f16*)(ws + 0);            // 832*512*2 = 851968
  f16* Wf1 = (f16*)(ws + 851968);       // 524288
  f16* Wf2 = (f16*)(ws + 1376256);      // 524288
  f16* Wf3 = (f16*)(ws + 1900544);      // 786432
  f16* Enc = (f16*)(ws + 2686976);      // 65536*64*2 = 8388608

  wfrag<<<dim3(208), 256, 0, stream>>>(W0, Wf0, 832, 512);
  wfrag<<<dim3(128), 256, 0, stream>>>(W1, Wf1, 512, 512);
  wfrag<<<dim3(128), 256, 0, stream>>>(W2, Wf2, 512, 512);
  wfrag<<<dim3(192), 256, 0, stream>>>(W3, Wf3, 512, 768);

  Scales sc;
  {
    double growth = exp((log(512.0) - log(16.0)) / 15.0);
    for (int l = 0; l < 16; ++l) sc.s[l] = (float)floor(16.0 * pow(growth, (double)l));
  }
  hash_enc<<<dim3(4096), 256, 0, stream>>>(t, cond, tab, Enc, sc);

  fused_mlp<<<dim3(512), 512, 0, stream>>>(x, Enc, Wf0, Wf1, Wf2, Wf3,
                                           b0, b1, b2, b3, out);
}

// Round 3
// 305.189 us; speedup vs baseline: 1.5954x; 1.5954x over previous
//
#include <hip/hip_runtime.h>
#include <hip/hip_bf16.h>
#include <math.h>

// Fully-fused hash-encode + 4-layer MLP, v3.
// Key changes vs v2: rolled K-loops (#pragma unroll 1) to fit I$,
// swapped-operand MFMA so D-frag holds 4 consecutive cols per lane
// (vector epilogue stores), enc fused in-kernel, 1-barrier L0 dbuf staging.

#define T_SIZE 524288   // 2^19
#define T_MASK (T_SIZE - 1)

typedef _Float16 f16;
typedef _Float16 f16x8 __attribute__((ext_vector_type(8)));
typedef _Float16 f16x4 __attribute__((ext_vector_type(4)));
typedef float f32x4 __attribute__((ext_vector_type(4)));

struct Scales { float s[16]; };

// ---------------- weight -> fragment-linear f16 ----------------
// Wf[frag][lane][8]: frag = nblk*(K/32)+ks; (lane,j) = W[ks*32+(lane>>4)*8+j][nblk*16+(lane&15)]
__global__ void wfrag(const float* __restrict__ W, f16* __restrict__ Wf, int K, int N) {
  int tid = blockIdx.x * 256 + threadIdx.x;
  int lane = tid & 63, frag = tid >> 6;
  int KS = K >> 5;
  int nblk = frag / KS, ks = frag - nblk * KS;
  if (nblk * 16 >= N) return;
  int n = nblk * 16 + (lane & 15);
  int kb = ks * 32 + (lane >> 4) * 8;
  f16x8 v;
#pragma unroll
  for (int j = 0; j < 8; ++j) v[j] = (f16)W[(size_t)(kb + j) * N + n];
  *(f16x8*)(Wf + (size_t)frag * 512 + lane * 8) = v;
}

__device__ __forceinline__ float silu_f(float v) {
  return v * __builtin_amdgcn_rcpf(1.f + __expf(-v));
}

// ---------------- fused MLP ----------------
__global__ __launch_bounds__(512, 2) void fused_mlp(
    const float* __restrict__ x, const float* __restrict__ t,
    const float* __restrict__ cond, const float* __restrict__ tables,
    const f16* __restrict__ Wf0, const f16* __restrict__ Wf1,
    const f16* __restrict__ Wf2, const f16* __restrict__ Wf3,
    const float* __restrict__ b0, const float* __restrict__ b1,
    const float* __restrict__ b2, const float* __restrict__ b3,
    float* __restrict__ out, Scales scl) {
  __shared__ f16 act[128 * 512];    // 128 KB, swizzled: elem = r*512 + (c ^ ((r&7)<<3))
  __shared__ f16 stg[2 * 128 * 32]; // 16 KB double-buffered L0 staging

  const int tid = threadIdx.x;
  const int wave = tid >> 6, lane = tid & 63;
  const int l16 = lane & 15, lhi = lane >> 4;
  const int rowBase = blockIdx.x * 128;
  const int sr = tid >> 2, sc = tid & 3;               // staging coords
  const int woff = sr * 32 + 8 * (sc ^ ((sr >> 1) & 3));

  // ---- per-thread hash-grid encode for the rows this thread stages ----
  // thread (sr,sc) needs enc chunks [sc*8..+8) (levels 2sc,2sc+1) and
  // [32+sc*8..+8) (levels 8+2sc, 8+2sc+1) of row sr.
  f16x8 er24, er25;
  {
    int row = rowBase + sr;
    float c0 = cond[2 * row], c1 = cond[2 * row + 1], c2 = t[row];
#pragma unroll
    for (int h = 0; h < 2; ++h) {
      f16x8 er;
#pragma unroll
      for (int d = 0; d < 2; ++d) {
        int l = h * 8 + sc * 2 + d;
        float s = scl.s[l];
        float xf0 = c0 * s, xf1 = c1 * s, xf2 = c2 * s;
        float xl0 = floorf(xf0), xl1 = floorf(xf1), xl2 = floorf(xf2);
        float w0 = xf0 - xl0, w1 = xf1 - xl1, w2 = xf2 - xl2;
        unsigned xi0 = (unsigned)xl0, xi1 = (unsigned)xl1, xi2 = (unsigned)xl2;
        const float4* tl = (const float4*)tables + (size_t)l * T_SIZE;
        float a0 = 0.f, a1 = 0.f, a2 = 0.f, a3 = 0.f;
#pragma unroll
        for (int c = 0; c < 8; ++c) {
          unsigned ax = (c >> 2) & 1u, ay = (c >> 1) & 1u, az = c & 1u;
          unsigned hh = (xi0 + ax) ^ ((xi1 + ay) * 2654435761u) ^ ((xi2 + az) * 805459861u);
          float4 f = tl[hh & T_MASK];
          float wcw = (ax ? w0 : 1.f - w0) * (ay ? w1 : 1.f - w1) * (az ? w2 : 1.f - w2);
          a0 += wcw * f.x; a1 += wcw * f.y; a2 += wcw * f.z; a3 += wcw * f.w;
        }
        er[d * 4 + 0] = (f16)a0; er[d * 4 + 1] = (f16)a1;
        er[d * 4 + 2] = (f16)a2; er[d * 4 + 3] = (f16)a3;
      }
      if (h == 0) er24 = er; else er25 = er;
    }
  }

  f32x4 acc[8][4];
  f16x8 bfA[4], bfB[4], af[8];

  // ================= Layer 0: K = 832 =================
#pragma unroll
  for (int mi = 0; mi < 8; ++mi)
#pragma unroll
    for (int ni = 0; ni < 4; ++ni) acc[mi][ni] = (f32x4){0.f, 0.f, 0.f, 0.f};

  {  // stage ks=0
    const float* xp = x + (size_t)(rowBase + sr) * 768 + sc * 8;
    float4 a = *(const float4*)xp, b = *(const float4*)(xp + 4);
    f16x8 v = { (f16)a.x, (f16)a.y, (f16)a.z, (f16)a.w,
                (f16)b.x, (f16)b.y, (f16)b.z, (f16)b.w };
    *(f16x8*)(stg + woff) = v;
  }
#pragma unroll
  for (int ni = 0; ni < 4; ++ni)
    bfA[ni] = *(const f16x8*)(Wf0 + ((size_t)(wave * 4 + ni) * 26) * 512 + lane * 8);
  __syncthreads();

#pragma unroll 1
  for (int ks = 0; ks < 26; ++ks) {
    const int nxt = ks + 1;
    f16x8 nv;
    if (nxt < 24) {
      const float* xp = x + (size_t)(rowBase + sr) * 768 + nxt * 32 + sc * 8;
      float4 a = *(const float4*)xp, b = *(const float4*)(xp + 4);
      nv = (f16x8){ (f16)a.x, (f16)a.y, (f16)a.z, (f16)a.w,
                    (f16)b.x, (f16)b.y, (f16)b.z, (f16)b.w };
    } else {
      nv = (nxt == 24) ? er24 : er25;
    }
    if (nxt < 26) {
#pragma unroll
      for (int ni = 0; ni < 4; ++ni)
        bfB[ni] = *(const f16x8*)(Wf0 + ((size_t)(wave * 4 + ni) * 26 + nxt) * 512 + lane * 8);
    }
    const int rb = (ks & 1) * 4096;
#pragma unroll
    for (int mi = 0; mi < 8; ++mi) {
      int r = mi * 16 + l16;
      af[mi] = *(const f16x8*)(stg + rb + r * 32 + 8 * (lhi ^ ((r >> 1) & 3)));
    }
    __builtin_amdgcn_s_setprio(1);
#pragma unroll
    for (int mi = 0; mi < 8; ++mi)
#pragma unroll
      for (int ni = 0; ni < 4; ++ni)
        acc[mi][ni] = __builtin_amdgcn_mfma_f32_16x16x32_f16(bfA[ni], af[mi], acc[mi][ni], 0, 0, 0);
    __builtin_amdgcn_s_setprio(0);
    if (nxt < 26) {
      *(f16x8*)(stg + (nxt & 1) * 4096 + woff) = nv;
#pragma unroll
      for (int ni = 0; ni < 4; ++ni) bfA[ni] = bfB[ni];
    }
    __syncthreads();
  }

  // epilogue -> act (bias + silu).  D-frag (swapped): row = mi*16+l16,
  // cols = wave*64 + ni*16 + lhi*4 + r  (4 consecutive -> b64 store)
  auto epi_act = [&](const float* __restrict__ bias) {
    __syncthreads();
#pragma unroll
    for (int mi = 0; mi < 8; ++mi) {
      const int row = mi * 16 + l16;
#pragma unroll
      for (int ni = 0; ni < 4; ++ni) {
        const int col = wave * 64 + ni * 16 + lhi * 4;
        float4 bv = *(const float4*)(bias + col);
        f16x4 o;
        o[0] = (f16)silu_f(acc[mi][ni][0] + bv.x);
        o[1] = (f16)silu_f(acc[mi][ni][1] + bv.y);
        o[2] = (f16)silu_f(acc[mi][ni][2] + bv.z);
        o[3] = (f16)silu_f(acc[mi][ni][3] + bv.w);
        *(f16x4*)(act + row * 512 + (col ^ ((row & 7) << 3))) = o;
      }
    }
    __syncthreads();
  };
  // NOTE: L0 loop already ended with a barrier; epi_act's leading barrier is
  // required for L1/L2 (in-place act overwrite) and harmless here.
  epi_act(b0);

  // ================= Layers 1,2,3: K = 512 =================
  auto kloop4 = [&](const f16* __restrict__ Wf) {
#pragma unroll
    for (int mi = 0; mi < 8; ++mi)
#pragma unroll
      for (int ni = 0; ni < 4; ++ni) acc[mi][ni] = (f32x4){0.f, 0.f, 0.f, 0.f};
#pragma unroll
    for (int ni = 0; ni < 4; ++ni)
      bfA[ni] = *(const f16x8*)(Wf + ((size_t)(wave * 4 + ni) * 16) * 512 + lane * 8);
#pragma unroll 1
    for (int ks = 0; ks < 16; ++ks) {
      if (ks < 15) {
#pragma unroll
        for (int ni = 0; ni < 4; ++ni)
          bfB[ni] = *(const f16x8*)(Wf + ((size_t)(wave * 4 + ni) * 16 + ks + 1) * 512 + lane * 8);
      }
#pragma unroll
      for (int mi = 0; mi < 8; ++mi) {
        int r = mi * 16 + l16;
        af[mi] = *(const f16x8*)(act + r * 512 + ((ks * 32 + lhi * 8) ^ ((r & 7) << 3)));
      }
      __builtin_amdgcn_s_setprio(1);
#pragma unroll
      for (int mi = 0; mi < 8; ++mi)
#pragma unroll
        for (int ni = 0; ni < 4; ++ni)
          acc[mi][ni] = __builtin_amdgcn_mfma_f32_16x16x32_f16(bfA[ni], af[mi], acc[mi][ni], 0, 0, 0);
      __builtin_amdgcn_s_setprio(0);
      if (ks < 15) {
#pragma unroll
        for (int ni = 0; ni < 4; ++ni) bfA[ni] = bfB[ni];
      }
    }
  };

  kloop4(Wf1); epi_act(b1);
  kloop4(Wf2); epi_act(b2);

  // Layer 3 pass A: cols 0..511
  kloop4(Wf3);
#pragma unroll
  for (int mi = 0; mi < 8; ++mi) {
    const size_t row = (size_t)(rowBase + mi * 16 + l16);
#pragma unroll
    for (int ni = 0; ni < 4; ++ni) {
      const int col = wave * 64 + ni * 16 + lhi * 4;
      float4 bv = *(const float4*)(b3 + col);
      float4 o = { acc[mi][ni][0] + bv.x, acc[mi][ni][1] + bv.y,
                   acc[mi][ni][2] + bv.z, acc[mi][ni][3] + bv.w };
      *(float4*)(out + row * 768 + col) = o;
    }
  }

  // Layer 3 pass B: cols 512..767 (2 frags/wave)
#pragma unroll
  for (int mi = 0; mi < 8; ++mi)
#pragma unroll
    for (int ni = 0; ni < 2; ++ni) acc[mi][ni] = (f32x4){0.f, 0.f, 0.f, 0.f};
#pragma unroll
  for (int ni = 0; ni < 2; ++ni)
    bfA[ni] = *(const f16x8*)(Wf3 + ((size_t)(32 + wave * 2 + ni) * 16) * 512 + lane * 8);
#pragma unroll 1
  for (int ks = 0; ks < 16; ++ks) {
    if (ks < 15) {
#pragma unroll
      for (int ni = 0; ni < 2; ++ni)
        bfB[ni] = *(const f16x8*)(Wf3 + ((size_t)(32 + wave * 2 + ni) * 16 + ks + 1) * 512 + lane * 8);
    }
#pragma unroll
    for (int mi = 0; mi < 8; ++mi) {
      int r = mi * 16 + l16;
      af[mi] = *(const f16x8*)(act + r * 512 + ((ks * 32 + lhi * 8) ^ ((r & 7) << 3)));
    }
    __builtin_amdgcn_s_setprio(1);
#pragma unroll
    for (int mi = 0; mi < 8; ++mi)
#pragma unroll
      for (int ni = 0; ni < 2; ++ni)
        acc[mi][ni] = __builtin_amdgcn_mfma_f32_16x16x32_f16(bfA[ni], af[mi], acc[mi][ni], 0, 0, 0);
    __builtin_amdgcn_s_setprio(0);
    if (ks < 15) {
#pragma unroll
      for (int ni = 0; ni < 2; ++ni) bfA[ni] = bfB[ni];
    }
  }
#pragma unroll
  for (int mi = 0; mi < 8; ++mi) {
    const size_t row = (size_t)(rowBase + mi * 16 + l16);
#pragma unroll
    for (int ni = 0; ni < 2; ++ni) {
      const int col = 512 + wave * 32 + ni * 16 + lhi * 4;
      float4 bv = *(const float4*)(b3 + col);
      float4 o = { acc[mi][ni][0] + bv.x, acc[mi][ni][1] + bv.y,
                   acc[mi][ni][2] + bv.z, acc[mi][ni][3] + bv.w };
      *(float4*)(out + row * 768 + col) = o;
    }
  }
}

// ---------------- launch ----------------
extern "C" void kernel_launch(void* const* d_in, const int* in_sizes, int n_in,
                              void* d_out, int out_size, void* d_ws, size_t ws_size,
                              hipStream_t stream) {
  const float* t    = (const float*)d_in[0];
  const float* x    = (const float*)d_in[1];
  const float* cond = (const float*)d_in[2];
  const float* tab  = (const float*)d_in[3];
  const float* W0   = (const float*)d_in[4];
  const float* b0   = (const float*)d_in[5];
  const float* W1   = (const float*)d_in[6];
  const float* b1   = (const float*)d_in[7];
  const float* W2   = (const float*)d_in[8];
  const float* b2   = (const float*)d_in[9];
  const float* W3   = (const float*)d_in[10];
  const float* b3   = (const float*)d_in[11];
  float* out = (float*)d_out;
  (void)in_sizes; (void)n_in; (void)out_size; (void)ws_size;

  char* ws = (char*)d_ws;
  f16* Wf0 = (f16*)(ws + 0);            // 832*512*2 = 851968
  f16* Wf1 = (f16*)(ws + 851968);       // 524288
  f16* Wf2 = (f16*)(ws + 1376256);      // 524288
  f16* Wf3 = (f16*)(ws + 1900544);      // 786432

  wfrag<<<dim3(208), 256, 0, stream>>>(W0, Wf0, 832, 512);
  wfrag<<<dim3(128), 256, 0, stream>>>(W1, Wf1, 512, 512);
  wfrag<<<dim3(128), 256, 0, stream>>>(W2, Wf2, 512, 512);
  wfrag<<<dim3(192), 256, 0, stream>>>(W3, Wf3, 512, 768);

  Scales sc;
  {
    double growth = exp((log(512.0) - log(16.0)) / 15.0);
    for (int l = 0; l < 16; ++l) sc.s[l] = (float)floor(16.0 * pow(growth, (double)l));
  }

  fused_mlp<<<dim3(512), 512, 0, stream>>>(x, t, cond, tab, Wf0, Wf1, Wf2, Wf3,
                                           b0, b1, b2, b3, out, sc);
}